// Round 1
// baseline (290.900 us; speedup 1.0000x reference)
//
#include <hip/hip_runtime.h>
#include <math.h>

#define NUM 2048
#define CDIM 256
#define NUM_LAYER 4

// ---------------- projection: out[b][n][oc] = sum_c W[oc][c] x[b][c][n] + bias[oc]
__global__ __launch_bounds__(256) void proj_kernel(
    const float* __restrict__ Wq, const float* __restrict__ bq,
    const float* __restrict__ Wk, const float* __restrict__ bk,
    const float* __restrict__ vf, const float* __restrict__ ef,
    float* __restrict__ QT, float* __restrict__ KT)
{
  const int z = blockIdx.z;
  const int b = z >> 1, m = z & 1;
  const float* __restrict__ Wmat = m ? Wk : Wq;
  const float* __restrict__ bias = m ? bk : bq;
  const float* __restrict__ x = (m ? ef : vf) + (size_t)b * CDIM * NUM;
  float* __restrict__ out = (m ? KT : QT) + (size_t)b * NUM * CDIM;

  const int n0 = blockIdx.x * 64;
  const int o0 = blockIdx.y * 64;
  __shared__ float Xs[32][65];   // [c][n], pad 65 -> compute reads 2-way max
  __shared__ float Ws[64][33];   // [oc][c], pad 33
  const int t = threadIdx.x;
  const int tx = t & 15, ty = t >> 4;

  float acc[4][4];
  #pragma unroll
  for (int a = 0; a < 4; a++)
    #pragma unroll
    for (int c = 0; c < 4; c++) acc[a][c] = 0.0f;

  for (int cc = 0; cc < CDIM; cc += 32) {
    #pragma unroll
    for (int e = 0; e < 2; e++) {
      int f = t * 2 + e;           // 0..511 float4s
      int row = f >> 4, c4 = f & 15;
      const float4 v = *(const float4*)(&x[(size_t)(cc + row) * NUM + n0 + c4 * 4]);
      Xs[row][c4*4+0] = v.x; Xs[row][c4*4+1] = v.y;
      Xs[row][c4*4+2] = v.z; Xs[row][c4*4+3] = v.w;
    }
    #pragma unroll
    for (int e = 0; e < 2; e++) {
      int f = t * 2 + e;
      int row = f >> 3, c4 = f & 7;
      const float4 v = *(const float4*)(&Wmat[(size_t)(o0 + row) * CDIM + cc + c4 * 4]);
      Ws[row][c4*4+0] = v.x; Ws[row][c4*4+1] = v.y;
      Ws[row][c4*4+2] = v.z; Ws[row][c4*4+3] = v.w;
    }
    __syncthreads();
    #pragma unroll
    for (int kk = 0; kk < 32; kk++) {
      float xv[4], wv[4];
      #pragma unroll
      for (int j = 0; j < 4; j++) xv[j] = Xs[kk][tx*4+j];
      #pragma unroll
      for (int j = 0; j < 4; j++) wv[j] = Ws[ty*4+j][kk];
      #pragma unroll
      for (int oi = 0; oi < 4; oi++)
        #pragma unroll
        for (int ni = 0; ni < 4; ni++)
          acc[oi][ni] = fmaf(wv[oi], xv[ni], acc[oi][ni]);
    }
    __syncthreads();
  }
  float bb[4];
  #pragma unroll
  for (int oi = 0; oi < 4; oi++) bb[oi] = bias[o0 + ty*4 + oi];
  #pragma unroll
  for (int ni = 0; ni < 4; ni++) {
    float4 v;
    v.x = acc[0][ni] + bb[0];
    v.y = acc[1][ni] + bb[1];
    v.z = acc[2][ni] + bb[2];
    v.w = acc[3][ni] + bb[3];
    *(float4*)(&out[(size_t)(n0 + tx*4 + ni) * CDIM + o0 + ty*4]) = v;
  }
}

// ---------------- score[b][o][i] = H0 * (1/8) * sum_h sigmoid(dot_h / sqrt(32))
__global__ __launch_bounds__(256) void score_kernel(
    const float* __restrict__ QT, const float* __restrict__ KT,
    const float* __restrict__ H0, float* __restrict__ score)
{
  const int b = blockIdx.z;
  const int i0 = blockIdx.x * 64;
  const int o0 = blockIdx.y * 64;
  const float* __restrict__ Qb = QT + (size_t)b * NUM * CDIM;
  const float* __restrict__ Kb = KT + (size_t)b * NUM * CDIM;
  __shared__ float Qs[64][33];
  __shared__ float Ks[64][33];
  const int t = threadIdx.x, tx = t & 15, ty = t >> 4;

  float ssum[4][4];
  #pragma unroll
  for (int a = 0; a < 4; a++)
    #pragma unroll
    for (int c = 0; c < 4; c++) ssum[a][c] = 0.0f;

  for (int h = 0; h < 8; h++) {
    #pragma unroll
    for (int e = 0; e < 2; e++) {
      int f = t * 2 + e;             // 0..511
      int row = f >> 3, c4 = f & 7;
      const float4 q = *(const float4*)(&Qb[(size_t)(o0 + row) * CDIM + h*32 + c4*4]);
      Qs[row][c4*4+0] = q.x; Qs[row][c4*4+1] = q.y;
      Qs[row][c4*4+2] = q.z; Qs[row][c4*4+3] = q.w;
      const float4 kv = *(const float4*)(&Kb[(size_t)(i0 + row) * CDIM + h*32 + c4*4]);
      Ks[row][c4*4+0] = kv.x; Ks[row][c4*4+1] = kv.y;
      Ks[row][c4*4+2] = kv.z; Ks[row][c4*4+3] = kv.w;
    }
    __syncthreads();
    float acc[4][4];
    #pragma unroll
    for (int a = 0; a < 4; a++)
      #pragma unroll
      for (int c = 0; c < 4; c++) acc[a][c] = 0.0f;
    #pragma unroll
    for (int kk = 0; kk < 32; kk++) {
      float qv[4], kvv[4];
      #pragma unroll
      for (int j = 0; j < 4; j++) qv[j] = Qs[ty*4+j][kk];
      #pragma unroll
      for (int j = 0; j < 4; j++) kvv[j] = Ks[tx*4+j][kk];
      #pragma unroll
      for (int oj = 0; oj < 4; oj++)
        #pragma unroll
        for (int ij = 0; ij < 4; ij++)
          acc[oj][ij] = fmaf(qv[oj], kvv[ij], acc[oj][ij]);
    }
    __syncthreads();
    #pragma unroll
    for (int oj = 0; oj < 4; oj++)
      #pragma unroll
      for (int ij = 0; ij < 4; ij++) {
        float a = acc[oj][ij] * 0.17677669529663687f;  // 1/sqrt(32)
        ssum[oj][ij] += 1.0f / (1.0f + expf(-a));
      }
  }
  #pragma unroll
  for (int oj = 0; oj < 4; oj++) {
    const int o = o0 + ty*4 + oj;
    const size_t base = ((size_t)b * NUM + o) * NUM + i0 + tx*4;
    const float4 h0 = *(const float4*)(&H0[base]);
    float4 sv;
    sv.x = h0.x * ssum[oj][0] * 0.125f;
    sv.y = h0.y * ssum[oj][1] * 0.125f;
    sv.z = h0.z * ssum[oj][2] * 0.125f;
    sv.w = h0.w * ssum[oj][3] * 0.125f;
    *(float4*)(&score[base]) = sv;
  }
}

// ---------------- exact k-th largest per row via radix select on float bits (all >= 0)
__global__ __launch_bounds__(256) void topk_kernel(
    const float* __restrict__ score, const int* __restrict__ iterp,
    float* __restrict__ amin)
{
  const int row = blockIdx.x;
  __shared__ unsigned int sv[NUM];
  __shared__ unsigned int hist[256];
  __shared__ unsigned int cum[256];
  __shared__ unsigned int s_sel;
  __shared__ unsigned int s_rem;
  const int t = threadIdx.x;
  const unsigned int* __restrict__ srow =
      (const unsigned int*)score + (size_t)row * NUM;
  #pragma unroll
  for (int j = 0; j < 8; j++) sv[t + 256*j] = srow[t + 256*j];

  const int it = iterp[0];
  int k = (int)((double)NUM * 0.1 * (double)(NUM_LAYER - 1 - it) + 0.5);
  if (k < 1) k = 1;
  if (k > NUM) k = NUM;

  unsigned int prefix = 0;
  unsigned int rem = (unsigned int)k;
  for (int pass = 3; pass >= 0; pass--) {
    const int shift = pass * 8;
    const unsigned int pmask = (pass == 3) ? 0u : (0xFFFFFFFFu << (shift + 8));
    hist[t] = 0;
    __syncthreads();
    #pragma unroll
    for (int j = 0; j < 8; j++) {
      unsigned int v = sv[t + 256*j];
      if ((v & pmask) == prefix)
        atomicAdd(&hist[(v >> shift) & 255u], 1u);
    }
    __syncthreads();
    cum[t] = hist[t];
    __syncthreads();
    for (int off = 1; off < 256; off <<= 1) {
      unsigned int add = (t + off < 256) ? cum[t + off] : 0u;
      __syncthreads();
      cum[t] += add;
      __syncthreads();
    }
    unsigned int above = (t < 255) ? cum[t + 1] : 0u;
    if (cum[t] >= rem && above < rem) { s_sel = (unsigned int)t; s_rem = rem - above; }
    __syncthreads();
    prefix |= (s_sel << shift);
    rem = s_rem;
    __syncthreads();
  }
  if (t == 0) amin[row] = __uint_as_float(prefix);
}

// ---------------- W/H + row sums -> Dv  (score -> W in place)
__global__ __launch_bounds__(256) void apply_kernel(
    float* __restrict__ scoreW, float* __restrict__ Hout,
    const float* __restrict__ amin, float* __restrict__ DvOut)
{
  const int row = blockIdx.x;
  const float am = amin[row];
  const int t = threadIdx.x;
  float cnt = 0.0f;
  #pragma unroll
  for (int j = 0; j < 8; j++) {
    const size_t idx = (size_t)row * NUM + t + 256*j;
    float s = scoreW[idx];
    float w = (s >= am) ? s : 0.0f;
    float hh = (w > 0.0f) ? 1.0f : 0.0f;  // H0==1 wherever score>0
    scoreW[idx] = w;
    Hout[idx] = hh;
    cnt += hh;
  }
  for (int off = 32; off > 0; off >>= 1) cnt += __shfl_down(cnt, off, 64);
  __shared__ float red[4];
  if ((t & 63) == 0) red[t >> 6] = cnt;
  __syncthreads();
  if (t == 0) {
    float tot = red[0] + red[1] + red[2] + red[3];
    DvOut[row] = 1.0f / (tot + 1e-10f);
  }
}

// ---------------- column partial sums (over o) of H and W
__global__ __launch_bounds__(256) void colsum_kernel(
    const float* __restrict__ Wmat, const float* __restrict__ Hmat,
    float* __restrict__ colH, float* __restrict__ colW)
{
  const int b = blockIdx.z;
  const int i = blockIdx.x * 256 + threadIdx.x;
  const int o0 = blockIdx.y * 128;
  float sh = 0.0f, sw = 0.0f;
  for (int o = 0; o < 128; o++) {
    size_t idx = ((size_t)b * NUM + o0 + o) * NUM + i;
    sh += Hmat[idx];
    sw += Wmat[idx];
  }
  atomicAdd(&colH[b * NUM + i], sh);
  atomicAdd(&colW[b * NUM + i], sw);
}

// ---------------- De = 1/(colH+eps); W_edge = colW / max(||colW||_2, 1e-12)
__global__ __launch_bounds__(1024) void finalize_kernel(
    const float* __restrict__ colH, const float* __restrict__ colW,
    float* __restrict__ De, float* __restrict__ We)
{
  const int b = blockIdx.x;
  const int t = threadIdx.x;
  float cw[2];
  float sq = 0.0f;
  #pragma unroll
  for (int j = 0; j < 2; j++) {
    int i = t + 1024*j;
    float ch = colH[b * NUM + i];
    De[b * NUM + i] = 1.0f / (ch + 1e-10f);
    cw[j] = colW[b * NUM + i];
    sq += cw[j] * cw[j];
  }
  for (int off = 32; off > 0; off >>= 1) sq += __shfl_down(sq, off, 64);
  __shared__ float red[16];
  __shared__ float s_nrm;
  if ((t & 63) == 0) red[t >> 6] = sq;
  __syncthreads();
  if (t == 0) {
    float tot = 0.0f;
    for (int i2 = 0; i2 < 16; i2++) tot += red[i2];
    s_nrm = fmaxf(sqrtf(tot), 1e-12f);
  }
  __syncthreads();
  #pragma unroll
  for (int j = 0; j < 2; j++)
    We[b * NUM + t + 1024*j] = cw[j] / s_nrm;
}

extern "C" void kernel_launch(void* const* d_in, const int* in_sizes, int n_in,
                              void* d_out, int out_size, void* d_ws, size_t ws_size,
                              hipStream_t stream) {
  const float* H0 = (const float*)d_in[0];
  const float* vf = (const float*)d_in[1];
  const float* ef = (const float*)d_in[2];
  const float* Wq = (const float*)d_in[3];
  const float* bq = (const float*)d_in[4];
  const float* Wk = (const float*)d_in[5];
  const float* bk = (const float*)d_in[6];
  const int* iter = (const int*)d_in[7];

  float* out = (float*)d_out;
  const size_t nH = (size_t)2 * NUM * NUM;
  float* Hout  = out;                 // (2,2048,2048)
  float* Wout  = out + nH;            // (2,2048,2048) — holds score temporarily
  float* DeOut = out + 2 * nH;        // (2,2048,1)
  float* DvOut = DeOut + 2 * NUM;     // (2,2048,1)
  float* WeOut = DvOut + 2 * NUM;     // (2,2048,1)

  float* colH = (float*)d_ws;         // 4096 floats
  float* colW = colH + 2 * NUM;       // 4096 floats
  float* amin = colW + 2 * NUM;       // 4096 floats

  // QT/KT (2*2048*256 floats each = 16 MB total) live in the H region until apply
  float* QT = Hout;
  float* KT = Hout + (size_t)2 * NUM * CDIM;

  hipMemsetAsync(d_ws, 0, (size_t)2 * 2 * NUM * sizeof(float), stream);

  proj_kernel<<<dim3(NUM/64, CDIM/64, 4), 256, 0, stream>>>(Wq, bq, Wk, bk, vf, ef, QT, KT);
  score_kernel<<<dim3(NUM/64, NUM/64, 2), 256, 0, stream>>>(QT, KT, H0, Wout);
  topk_kernel<<<dim3(2 * NUM), 256, 0, stream>>>(Wout, iter, amin);
  apply_kernel<<<dim3(2 * NUM), 256, 0, stream>>>(Wout, Hout, amin, DvOut);
  colsum_kernel<<<dim3(NUM/256, NUM/128, 2), 256, 0, stream>>>(Wout, Hout, colH, colW);
  finalize_kernel<<<dim3(2), 1024, 0, stream>>>(colH, colW, DeOut, WeOut);
}

// Round 2
// 227.310 us; speedup vs baseline: 1.2798x; 1.2798x over previous
//
#include <hip/hip_runtime.h>
#include <math.h>

#define NUM 2048
#define CDIM 256
#define NUM_LAYER 4

// ---------------- projection: out[b][n][oc] = sum_c W[oc][c] x[b][c][n] + bias[oc]
__global__ __launch_bounds__(256) void proj_kernel(
    const float* __restrict__ Wq, const float* __restrict__ bq,
    const float* __restrict__ Wk, const float* __restrict__ bk,
    const float* __restrict__ vf, const float* __restrict__ ef,
    float* __restrict__ QT, float* __restrict__ KT)
{
  const int z = blockIdx.z;
  const int b = z >> 1, m = z & 1;
  const float* __restrict__ Wmat = m ? Wk : Wq;
  const float* __restrict__ bias = m ? bk : bq;
  const float* __restrict__ x = (m ? ef : vf) + (size_t)b * CDIM * NUM;
  float* __restrict__ out = (m ? KT : QT) + (size_t)b * NUM * CDIM;

  const int n0 = blockIdx.x * 64;
  const int o0 = blockIdx.y * 64;
  __shared__ float Xs[32][65];
  __shared__ float Ws[64][33];
  const int t = threadIdx.x;
  const int tx = t & 15, ty = t >> 4;

  float acc[4][4];
  #pragma unroll
  for (int a = 0; a < 4; a++)
    #pragma unroll
    for (int c = 0; c < 4; c++) acc[a][c] = 0.0f;

  for (int cc = 0; cc < CDIM; cc += 32) {
    #pragma unroll
    for (int e = 0; e < 2; e++) {
      int f = t * 2 + e;
      int row = f >> 4, c4 = f & 15;
      const float4 v = *(const float4*)(&x[(size_t)(cc + row) * NUM + n0 + c4 * 4]);
      Xs[row][c4*4+0] = v.x; Xs[row][c4*4+1] = v.y;
      Xs[row][c4*4+2] = v.z; Xs[row][c4*4+3] = v.w;
    }
    #pragma unroll
    for (int e = 0; e < 2; e++) {
      int f = t * 2 + e;
      int row = f >> 3, c4 = f & 7;
      const float4 v = *(const float4*)(&Wmat[(size_t)(o0 + row) * CDIM + cc + c4 * 4]);
      Ws[row][c4*4+0] = v.x; Ws[row][c4*4+1] = v.y;
      Ws[row][c4*4+2] = v.z; Ws[row][c4*4+3] = v.w;
    }
    __syncthreads();
    #pragma unroll
    for (int kk = 0; kk < 32; kk++) {
      float xv[4], wv[4];
      #pragma unroll
      for (int j = 0; j < 4; j++) xv[j] = Xs[kk][tx*4+j];
      #pragma unroll
      for (int j = 0; j < 4; j++) wv[j] = Ws[ty*4+j][kk];
      #pragma unroll
      for (int oi = 0; oi < 4; oi++)
        #pragma unroll
        for (int ni = 0; ni < 4; ni++)
          acc[oi][ni] = fmaf(wv[oi], xv[ni], acc[oi][ni]);
    }
    __syncthreads();
  }
  float bb[4];
  #pragma unroll
  for (int oi = 0; oi < 4; oi++) bb[oi] = bias[o0 + ty*4 + oi];
  #pragma unroll
  for (int ni = 0; ni < 4; ni++) {
    float4 v;
    v.x = acc[0][ni] + bb[0];
    v.y = acc[1][ni] + bb[1];
    v.z = acc[2][ni] + bb[2];
    v.w = acc[3][ni] + bb[3];
    *(float4*)(&out[(size_t)(n0 + tx*4 + ni) * CDIM + o0 + ty*4]) = v;
  }
}

// ---------------- score[b][o][i] = H0 * (1/8) * sum_h sigmoid(dot_h / sqrt(32))
// 128x128 tile, 512 threads, each computes 4(o) x 8(i). LDS stored [k][n] so
// fragments are ds_read_b128.
__global__ __launch_bounds__(512) void score_kernel(
    const float* __restrict__ QT, const float* __restrict__ KT,
    const float* __restrict__ H0, float* __restrict__ score)
{
  const int b = blockIdx.z;
  const int i0 = blockIdx.x * 128;
  const int o0 = blockIdx.y * 128;
  const float* __restrict__ Qb = QT + (size_t)b * NUM * CDIM;
  const float* __restrict__ Kb = KT + (size_t)b * NUM * CDIM;
  __shared__ float Qs[32][128];   // [k][o]
  __shared__ float Ks[32][128];   // [k][i]
  const int t = threadIdx.x, tx = t & 15, ty = t >> 4;  // tx: i (8 each), ty: o (4 each)

  float ssum[4][8];
  #pragma unroll
  for (int a = 0; a < 4; a++)
    #pragma unroll
    for (int c = 0; c < 8; c++) ssum[a][c] = 0.0f;

  const float SC = -1.4426950408889634f * 0.17677669529663687f;  // -log2(e)/sqrt(32)

  for (int h = 0; h < 8; h++) {
    #pragma unroll
    for (int e = 0; e < 2; e++) {
      int f = t + 512 * e;            // 0..1023
      int row = f >> 3, c4 = f & 7;
      const float4 q = *(const float4*)(&Qb[(size_t)(o0 + row) * CDIM + h*32 + c4*4]);
      Qs[c4*4+0][row] = q.x; Qs[c4*4+1][row] = q.y;
      Qs[c4*4+2][row] = q.z; Qs[c4*4+3][row] = q.w;
      const float4 kv = *(const float4*)(&Kb[(size_t)(i0 + row) * CDIM + h*32 + c4*4]);
      Ks[c4*4+0][row] = kv.x; Ks[c4*4+1][row] = kv.y;
      Ks[c4*4+2][row] = kv.z; Ks[c4*4+3][row] = kv.w;
    }
    __syncthreads();
    float acc[4][8];
    #pragma unroll
    for (int a = 0; a < 4; a++)
      #pragma unroll
      for (int c = 0; c < 8; c++) acc[a][c] = 0.0f;
    #pragma unroll 4
    for (int kk = 0; kk < 32; kk++) {
      const float4 qf = *(const float4*)(&Qs[kk][ty*4]);
      const float4 k0 = *(const float4*)(&Ks[kk][tx*8]);
      const float4 k1 = *(const float4*)(&Ks[kk][tx*8+4]);
      const float qv[4] = {qf.x, qf.y, qf.z, qf.w};
      const float kv[8] = {k0.x, k0.y, k0.z, k0.w, k1.x, k1.y, k1.z, k1.w};
      #pragma unroll
      for (int oj = 0; oj < 4; oj++)
        #pragma unroll
        for (int ij = 0; ij < 8; ij++)
          acc[oj][ij] = fmaf(qv[oj], kv[ij], acc[oj][ij]);
    }
    __syncthreads();
    #pragma unroll
    for (int oj = 0; oj < 4; oj++)
      #pragma unroll
      for (int ij = 0; ij < 8; ij++) {
        float z = __builtin_amdgcn_exp2f(acc[oj][ij] * SC);
        ssum[oj][ij] += __builtin_amdgcn_rcpf(1.0f + z);
      }
  }
  #pragma unroll
  for (int oj = 0; oj < 4; oj++) {
    const int o = o0 + ty*4 + oj;
    const size_t base = ((size_t)b * NUM + o) * NUM + i0 + tx*8;
    const float4 h0a = *(const float4*)(&H0[base]);
    const float4 h0b = *(const float4*)(&H0[base + 4]);
    float4 sa, sb;
    sa.x = h0a.x * ssum[oj][0] * 0.125f;
    sa.y = h0a.y * ssum[oj][1] * 0.125f;
    sa.z = h0a.z * ssum[oj][2] * 0.125f;
    sa.w = h0a.w * ssum[oj][3] * 0.125f;
    sb.x = h0b.x * ssum[oj][4] * 0.125f;
    sb.y = h0b.y * ssum[oj][5] * 0.125f;
    sb.z = h0b.z * ssum[oj][6] * 0.125f;
    sb.w = h0b.w * ssum[oj][7] * 0.125f;
    *(float4*)(&score[base]) = sa;
    *(float4*)(&score[base + 4]) = sb;
  }
}

// ---------------- fused: exact k-th largest (radix select on float bits, all >= 0)
// + W/H write + row count -> Dv. Row values live in registers.
__global__ __launch_bounds__(256) void topk_apply_kernel(
    float* __restrict__ scoreW, float* __restrict__ Hout,
    const int* __restrict__ iterp, float* __restrict__ DvOut)
{
  const int row = blockIdx.x;
  __shared__ unsigned int hist[4][256];
  __shared__ unsigned int cum[257];
  __shared__ unsigned int s_sel, s_rem;
  __shared__ float red[4];
  const int t = threadIdx.x;
  const int wid = t >> 6, lane = t & 63;
  unsigned int* __restrict__ srow = (unsigned int*)scoreW + (size_t)row * NUM;

  unsigned int v[8];
  #pragma unroll
  for (int j = 0; j < 8; j++) v[j] = srow[t + 256*j];

  const int it = iterp[0];
  int k = (int)((double)NUM * 0.1 * (double)(NUM_LAYER - 1 - it) + 0.5);
  if (k < 1) k = 1;
  if (k > NUM) k = NUM;

  unsigned int prefix = 0;
  unsigned int rem = (unsigned int)k;
  unsigned int* hflat = &hist[0][0];

  for (int pass = 3; pass >= 0; pass--) {
    const int shift = pass * 8;
    const unsigned int pmask = (pass == 3) ? 0u : (0xFFFFFFFFu << (shift + 8));
    #pragma unroll
    for (int j = 0; j < 4; j++) hflat[t + 256*j] = 0;
    __syncthreads();
    unsigned int zc = 0;
    #pragma unroll
    for (int j = 0; j < 8; j++) {
      unsigned int val = v[j];
      if ((val & pmask) == prefix) {
        unsigned int bin = (val >> shift) & 255u;
        if (bin) atomicAdd(&hist[wid][bin], 1u);
        else zc++;
      }
    }
    // wave-aggregate the bin-0 count (zeros cluster heavily)
    #pragma unroll
    for (int off = 32; off > 0; off >>= 1) zc += __shfl_down(zc, off, 64);
    if (lane == 0 && zc) atomicAdd(&hist[wid][0], zc);
    __syncthreads();
    // wave 0: merge 4 copies + suffix-sum 256 bins (4 per lane, shfl scan)
    if (t < 64) {
      unsigned int T[4], s[4];
      #pragma unroll
      for (int q = 0; q < 4; q++)
        T[q] = hist[0][t*4+q] + hist[1][t*4+q] + hist[2][t*4+q] + hist[3][t*4+q];
      s[3] = T[3];
      s[2] = T[2] + s[3];
      s[1] = T[1] + s[2];
      s[0] = T[0] + s[1];
      unsigned int tot = s[0];
      #pragma unroll
      for (int off = 1; off < 64; off <<= 1) {
        unsigned int y = __shfl_down(tot, off, 64);
        if (lane + off < 64) tot += y;
      }
      const unsigned int above_chunk = tot - s[0];
      #pragma unroll
      for (int q = 0; q < 4; q++) cum[t*4+q] = s[q] + above_chunk;
      if (t == 0) cum[256] = 0;
    }
    __syncthreads();
    unsigned int c = cum[t], above = cum[t + 1];
    if (c >= rem && above < rem) { s_sel = (unsigned int)t; s_rem = rem - above; }
    __syncthreads();
    prefix |= (s_sel << shift);
    rem = s_rem;
    __syncthreads();
  }

  // apply: W = (score >= amin) ? score : 0 ; H = (W>0) ; Dv = 1/(rowsum(H)+eps)
  const unsigned int amin = prefix;
  float* __restrict__ Hrow = Hout + (size_t)row * NUM;
  float cnt = 0.0f;
  #pragma unroll
  for (int j = 0; j < 8; j++) {
    unsigned int val = v[j];
    unsigned int w = (val >= amin) ? val : 0u;
    float hh = (w != 0u) ? 1.0f : 0.0f;
    srow[t + 256*j] = w;
    Hrow[t + 256*j] = hh;
    cnt += hh;
  }
  #pragma unroll
  for (int off = 32; off > 0; off >>= 1) cnt += __shfl_down(cnt, off, 64);
  if (lane == 0) red[wid] = cnt;
  __syncthreads();
  if (t == 0) {
    float tot = red[0] + red[1] + red[2] + red[3];
    DvOut[row] = 1.0f / (tot + 1e-10f);
  }
}

// ---------------- column partial sums over o; colH derived from W>0
__global__ __launch_bounds__(256) void colsum_kernel(
    const float* __restrict__ Wmat,
    float* __restrict__ colH, float* __restrict__ colW)
{
  const int b = blockIdx.z;
  const int i = blockIdx.x * 256 + threadIdx.x;
  const int o0 = blockIdx.y * 128;
  float sh = 0.0f, sw = 0.0f;
  for (int o = 0; o < 128; o++) {
    size_t idx = ((size_t)b * NUM + o0 + o) * NUM + i;
    float w = Wmat[idx];
    sw += w;
    sh += (w > 0.0f) ? 1.0f : 0.0f;
  }
  atomicAdd(&colH[b * NUM + i], sh);
  atomicAdd(&colW[b * NUM + i], sw);
}

// ---------------- De = 1/(colH+eps); W_edge = colW / max(||colW||_2, 1e-12)
__global__ __launch_bounds__(1024) void finalize_kernel(
    const float* __restrict__ colH, const float* __restrict__ colW,
    float* __restrict__ De, float* __restrict__ We)
{
  const int b = blockIdx.x;
  const int t = threadIdx.x;
  float cw[2];
  float sq = 0.0f;
  #pragma unroll
  for (int j = 0; j < 2; j++) {
    int i = t + 1024*j;
    float ch = colH[b * NUM + i];
    De[b * NUM + i] = 1.0f / (ch + 1e-10f);
    cw[j] = colW[b * NUM + i];
    sq += cw[j] * cw[j];
  }
  for (int off = 32; off > 0; off >>= 1) sq += __shfl_down(sq, off, 64);
  __shared__ float red[16];
  __shared__ float s_nrm;
  if ((t & 63) == 0) red[t >> 6] = sq;
  __syncthreads();
  if (t == 0) {
    float tot = 0.0f;
    for (int i2 = 0; i2 < 16; i2++) tot += red[i2];
    s_nrm = fmaxf(sqrtf(tot), 1e-12f);
  }
  __syncthreads();
  #pragma unroll
  for (int j = 0; j < 2; j++)
    We[b * NUM + t + 1024*j] = cw[j] / s_nrm;
}

extern "C" void kernel_launch(void* const* d_in, const int* in_sizes, int n_in,
                              void* d_out, int out_size, void* d_ws, size_t ws_size,
                              hipStream_t stream) {
  const float* H0 = (const float*)d_in[0];
  const float* vf = (const float*)d_in[1];
  const float* ef = (const float*)d_in[2];
  const float* Wq = (const float*)d_in[3];
  const float* bq = (const float*)d_in[4];
  const float* Wk = (const float*)d_in[5];
  const float* bk = (const float*)d_in[6];
  const int* iter = (const int*)d_in[7];

  float* out = (float*)d_out;
  const size_t nH = (size_t)2 * NUM * NUM;
  float* Hout  = out;                 // (2,2048,2048)
  float* Wout  = out + nH;            // (2,2048,2048) — holds score temporarily
  float* DeOut = out + 2 * nH;        // (2,2048,1)
  float* DvOut = DeOut + 2 * NUM;     // (2,2048,1)
  float* WeOut = DvOut + 2 * NUM;     // (2,2048,1)

  float* colH = (float*)d_ws;         // 4096 floats
  float* colW = colH + 2 * NUM;       // 4096 floats

  // QT/KT (16 MB) live in the H region until topk_apply overwrites it
  float* QT = Hout;
  float* KT = Hout + (size_t)2 * NUM * CDIM;

  hipMemsetAsync(d_ws, 0, (size_t)2 * 2 * NUM * sizeof(float), stream);

  proj_kernel<<<dim3(NUM/64, CDIM/64, 4), 256, 0, stream>>>(Wq, bq, Wk, bk, vf, ef, QT, KT);
  score_kernel<<<dim3(NUM/128, NUM/128, 2), 512, 0, stream>>>(QT, KT, H0, Wout);
  topk_apply_kernel<<<dim3(2 * NUM), 256, 0, stream>>>(Wout, Hout, iter, DvOut);
  colsum_kernel<<<dim3(NUM/256, NUM/128, 2), 256, 0, stream>>>(Wout, colH, colW);
  finalize_kernel<<<dim3(2), 1024, 0, stream>>>(colH, colW, DeOut, WeOut);
}